// Round 7
// baseline (256.763 us; speedup 1.0000x reference)
//
#include <hip/hip_runtime.h>
#include <stdint.h>

#define K_CODES   8192
#define N_PIX     16384
#define D_DIM     64
#define EM_STRIDE 8193   // original embed row stride (K+1)
#define KSUB      8      // 256-code subtiles per block (k-persistence)
#define KGRP      4      // 8192 / (KSUB*256)
#define DCH       32     // d-chunk rows staged per barrier pair (32 KB)
#define OUT_QUANT 0
#define OUT_DMIN  1048576
#define OUT_IND   (1048576 + 16384)

// async global->LDS, 16B per lane, wave-uniform LDS base + lane*16 dest
__device__ __forceinline__ void gld_lds16(const float* g, float* l) {
    __builtin_amdgcn_global_load_lds(
        (const __attribute__((address_space(1))) uint32_t*)g,
        (__attribute__((address_space(3))) uint32_t*)l, 16, 0, 0);
}

// ---------------------------------------------------------------------------
// Kernel 1: per-code squared norms (stale -> +huge, never selected) and a
// stride-8192 copy of embed so tile staging can use aligned 16B loads.
// ---------------------------------------------------------------------------
__global__ __launch_bounds__(256)
void vq_prep(const float* __restrict__ embed,
             const int* __restrict__ cnt,
             float* __restrict__ ec,     // [64][8192]
             float* __restrict__ cn) {   // [8192]
    int k = blockIdx.x * 256 + threadIdx.x;
    float s = 0.f;
#pragma unroll
    for (int d = 0; d < D_DIM; ++d) {
        float v = embed[d * EM_STRIDE + k];
        ec[d * K_CODES + k] = v;
        s = fmaf(v, v, s);
    }
    cn[k] = (cnt[k] < 1) ? 1.0e30f : s;
}

// ---------------------------------------------------------------------------
// Kernel 2: fp32 distance GEMM + fused running argmin.
// 256 thr = 4 waves. Wave owns 16 rows: x values are wave-uniform scalars
// (SGPR operand feeds the FMA directly -- 1 SGPR read/VALU instr is legal).
// Lane owns 4 codes. One ds_read_b128 per 64 FMA instrs: LDS-pipe occupancy
// ~37% (was 75% across R4/R6 -- the measured shared limiter).
// acc[16][4] = 64 VGPR; ~112 total, fits 4 blocks/CU at 32 KB LDS.
// Grid 1024 = exactly one generation of 4 blocks/CU, zero tail.
// ---------------------------------------------------------------------------
__global__ __launch_bounds__(256, 4)
void vq_dist_tile(const float* __restrict__ x,     // [64][16384]
                  const float* __restrict__ ec,    // [64][8192]
                  const float* __restrict__ cn,    // [8192] masked norms
                  float* __restrict__ pmin,        // [KGRP][16384]
                  int*   __restrict__ pidx) {      // [KGRP][16384]
    __shared__ float es[DCH][256];

    const int nb  = blockIdx.x & 255;    // 256 row blocks (64 rows each)
    const int kg  = blockIdx.x >> 8;     // 4 k-groups of 2048 codes
    const int n0  = nb * 64;
    const int kgb = kg * (KSUB * 256);
    const int t    = threadIdx.x;
    const int lane = t & 63;
    const int w    = t >> 6;             // wave 0..3
    const int wu   = __builtin_amdgcn_readfirstlane(w);

    // x rows for this wave: n0 + wu*16 .. +15 (uniform across all 64 lanes)
    const float* __restrict__ xw = x + n0 + wu * 16;

    float acc[16][4];
    float bd[16];
    int   bix[16];
#pragma unroll
    for (int r = 0; r < 16; ++r) {
        bd[r] = 3.0e38f; bix[r] = 0;
#pragma unroll
        for (int c = 0; c < 4; ++c) acc[r][c] = 0.f;
    }

    for (int st = 0; st < KSUB; ++st) {
        const int k0 = kgb + st * 256;

        for (int ch = 0; ch < 2; ++ch) {
            const int d0 = ch * DCH;
            __syncthreads();             // previous e-chunk fully consumed
            // ---- stage e chunk [32][256]: 32 x 1KB instrs, 8 per wave ----
#pragma unroll
            for (int j = 0; j < 8; ++j) {
                int rr = j * 4 + w;      // chunk row 0..31, uniform per wave
                gld_lds16(ec + (d0 + rr) * K_CODES + k0 + lane * 4,
                          &es[rr][0]);
            }
            __syncthreads();             // vmcnt(0) drain + barrier
            // ---- compute: 32 d-steps, 64 FMA instrs each ----
            const float* esl = &es[0][0] + lane * 4;
            const float* xc  = xw + d0 * N_PIX;
#pragma unroll 2
            for (int d = 0; d < DCH; ++d) {
                float4 ea = *(const float4*)(esl + d * 256);
                const float* xr = xc + d * N_PIX;
                float xv[16];
#pragma unroll
                for (int r = 0; r < 16; ++r) xv[r] = xr[r];
#pragma unroll
                for (int r = 0; r < 16; ++r) {
                    acc[r][0] = fmaf(xv[r], ea.x, acc[r][0]);
                    acc[r][1] = fmaf(xv[r], ea.y, acc[r][1]);
                    acc[r][2] = fmaf(xv[r], ea.z, acc[r][2]);
                    acc[r][3] = fmaf(xv[r], ea.w, acc[r][3]);
                }
            }
        }

        // ---- per-subtile epilogue: dist = cn - 2*dot, running argmin ----
        const int kb = k0 + lane * 4;                 // lane's 4 codes
        float4 cn4 = *(const float4*)(cn + kb);
        float cnv[4] = {cn4.x, cn4.y, cn4.z, cn4.w};
#pragma unroll
        for (int r = 0; r < 16; ++r) {
#pragma unroll
            for (int c = 0; c < 4; ++c) {             // ascending k: strict <
                float dist = fmaf(-2.f, acc[r][c], cnv[c]);
                if (dist < bd[r]) { bd[r] = dist; bix[r] = kb + c; }
                acc[r][c] = 0.f;
            }
        }
    }

    // ---- once per block: butterfly-min across the 64 lanes, write ----
#pragma unroll
    for (int r = 0; r < 16; ++r) {
        float d = bd[r];
        int   i = bix[r];
#pragma unroll
        for (int m = 1; m < 64; m <<= 1) {
            float od = __shfl_xor(d, m, 64);
            int   oi = __shfl_xor(i, m, 64);
            if (od < d || (od == d && oi < i)) { d = od; i = oi; }
        }
        if (lane == 0) {
            pmin[kg * N_PIX + n0 + wu * 16 + r] = d;
            pidx[kg * N_PIX + n0 + wu * 16 + r] = i;
        }
    }
}

// ---------------------------------------------------------------------------
// Kernel 3: reduce 4 k-group partials per row, add ||x||^2, gather winning
// code column, write all three outputs.
// ---------------------------------------------------------------------------
__global__ __launch_bounds__(256)
void vq_finalize(const float* __restrict__ x,
                 const float* __restrict__ ec,
                 const float* __restrict__ pmin,
                 const int*   __restrict__ pidx,
                 float* __restrict__ out) {
    int n = blockIdx.x * 256 + threadIdx.x;   // 0..16383
    float best = 3.0e38f;
    int   bi   = 0x7fffffff;
#pragma unroll
    for (int kb = 0; kb < KGRP; ++kb) {
        float m = pmin[kb * N_PIX + n];
        int   i = pidx[kb * N_PIX + n];
        if (m < best || (m == best && i < bi)) { best = m; bi = i; }
    }
    float rn = 0.f;
#pragma unroll
    for (int d = 0; d < D_DIM; ++d) {
        float v = x[d * N_PIX + n];
        rn = fmaf(v, v, rn);
    }
    out[OUT_DMIN + n] = best + rn;
    out[OUT_IND  + n] = (float)bi;
#pragma unroll
    for (int d = 0; d < D_DIM; ++d)
        out[OUT_QUANT + d * N_PIX + n] = ec[d * K_CODES + bi];
}

// ---------------------------------------------------------------------------
extern "C" void kernel_launch(void* const* d_in, const int* in_sizes, int n_in,
                              void* d_out, int out_size, void* d_ws, size_t ws_size,
                              hipStream_t stream) {
    const float* x     = (const float*)d_in[0];   // [1,64,128,128]
    const float* embed = (const float*)d_in[1];   // [64,8193]
    const int*   cnt   = (const int*)d_in[2];     // [8192]
    float* out = (float*)d_out;

    // workspace layout
    float* ec   = (float*)d_ws;                                      // 2 MB
    float* cn   = (float*)((char*)d_ws + (size_t)2 * 1024 * 1024);   // 32 KB
    float* pmin = (float*)((char*)d_ws + (size_t)2 * 1024 * 1024 + 32768);
    int*   pidx = (int*)((char*)pmin + (size_t)KGRP * N_PIX * 4);

    vq_prep<<<K_CODES / 256, 256, 0, stream>>>(embed, cnt, ec, cn);
    vq_dist_tile<<<KGRP * 256, 256, 0, stream>>>(x, ec, cn, pmin, pidx);
    vq_finalize<<<N_PIX / 256, 256, 0, stream>>>(x, ec, pmin, pidx, out);
}

// Round 8
// 127.467 us; speedup vs baseline: 2.0143x; 2.0143x over previous
//
#include <hip/hip_runtime.h>
#include <stdint.h>

#define NPIX   16384
#define KC     8192
#define DD     64
#define EMS    8193          // embed row stride (K+1)
#define OUT_QUANT 0
#define OUT_DMIN  1048576
#define OUT_IND   (1048576 + 16384)

typedef _Float16 f16;
typedef _Float16 f16x8 __attribute__((ext_vector_type(8)));
typedef float    f32x4 __attribute__((ext_vector_type(4)));
typedef unsigned long long u64;

// async global->LDS, 16B/lane; dest = wave-uniform base (+lane*16 by HW)
__device__ __forceinline__ void gld_lds16(const void* g, void* l) {
    __builtin_amdgcn_global_load_lds(
        (const __attribute__((address_space(1))) uint32_t*)g,
        (__attribute__((address_space(3))) uint32_t*)l, 16, 0, 0);
}

// ---------------------------------------------------------------------------
// Prep X: split fp32 x into f16 hi/lo, store k-slot-blocked A3[16][NPIX][8].
// Slots 0..7 = Xh (d = slot*8..+7), slots 8..15 = Xl.
// ---------------------------------------------------------------------------
__global__ __launch_bounds__(256)
void vq_prep_x(const float* __restrict__ x, f16* __restrict__ A3) {
    int n = blockIdx.x * 256 + threadIdx.x;
#pragma unroll
    for (int s = 0; s < 8; ++s) {
        f16x8 hv, lv;
#pragma unroll
        for (int j = 0; j < 8; ++j) {
            float v = x[(s * 8 + j) * NPIX + n];
            f16 h = (f16)v;
            hv[j] = h;
            lv[j] = (f16)(v - (float)h);
        }
        *(f16x8*)&A3[((u64)(s)     * NPIX + n) * 8] = hv;
        *(f16x8*)&A3[((u64)(s + 8) * NPIX + n) * 8] = lv;
    }
}

// ---------------------------------------------------------------------------
// Prep E: split embed into f16 hi/lo B3[16][KC][8] + masked norms cn.
// ---------------------------------------------------------------------------
__global__ __launch_bounds__(256)
void vq_prep_e(const float* __restrict__ em, const int* __restrict__ cnt,
               f16* __restrict__ B3, float* __restrict__ cn) {
    int k = blockIdx.x * 256 + threadIdx.x;
    float s2 = 0.f;
#pragma unroll
    for (int s = 0; s < 8; ++s) {
        f16x8 hv, lv;
#pragma unroll
        for (int j = 0; j < 8; ++j) {
            float v = em[(s * 8 + j) * EMS + k];
            f16 h = (f16)v;
            hv[j] = h;
            lv[j] = (f16)(v - (float)h);
            s2 = fmaf(v, v, s2);
        }
        *(f16x8*)&B3[((u64)(s)     * KC + k) * 8] = hv;
        *(f16x8*)&B3[((u64)(s + 8) * KC + k) * 8] = lv;
    }
    cn[k] = (cnt[k] < 1) ? 1.0e30f : s2;
}

// ---------------------------------------------------------------------------
// MFMA distance GEMM + fused per-group packed argmin.
// Split product: x.e = Xh.Eh + Xl.Eh + Xh.El  -> 6 K-steps of 32 (K=192).
// Block: 128 pixels x 512 codes (4 subtiles of 128), 4 waves, wave quad 64x64.
// LDS As/Bs: [4 kslot][128][8] f16 (8 KB each), staged via global_load_lds
// from k-slot-blocked A3/B3 (linear dest, coalesced src, conflict-free reads).
// Epilogue packs dist(+1024 bias) and col into u64, running min in regs,
// 16-lane shuffle reduce, one pk write per (group = nb*2+wc, row).
// ---------------------------------------------------------------------------
__global__ __launch_bounds__(256, 3)
void vq_mfma(const f16* __restrict__ A3, const f16* __restrict__ B3,
             const float* __restrict__ cn, u64* __restrict__ pk) {
    __shared__ f16 As[4096];   // [4][128][8]
    __shared__ f16 Bs[4096];

    const int bid = blockIdx.x;
    const int nb  = bid >> 7;        // 0..15 (512-code groups)
    const int mb  = bid & 127;       // 0..127 (128-pixel tiles)
    const int m0  = mb * 128;
    const int n0  = nb * 512;
    const int t = threadIdx.x, lane = t & 63, w = t >> 6;
    const int wr = w >> 1, wc = w & 1;
    const int l15 = lane & 15, l4 = lane >> 4;

    u64 rmin[16];
#pragma unroll
    for (int i = 0; i < 16; ++i) rmin[i] = ~0ull;

    const f32x4 zero4 = {0.f, 0.f, 0.f, 0.f};

#pragma unroll 1
    for (int ns = 0; ns < 4; ++ns) {
        const int nsub = n0 + ns * 128;
        f32x4 acc[4][4];
#pragma unroll
        for (int m = 0; m < 4; ++m)
#pragma unroll
            for (int n = 0; n < 4; ++n) acc[m][n] = zero4;

        const int sa_t[6] = {0, 4, 8, 12, 0, 4};
        const int sb_t[6] = {0, 4, 0, 4, 8, 12};
#pragma unroll 1
        for (int kt = 0; kt < 6; ++kt) {
            const int sa = sa_t[kt], sb = sb_t[kt];
            __syncthreads();               // LDS free (reads drained)
#pragma unroll
            for (int j = 0; j < 2; ++j) {
                gld_lds16(A3 + ((u64)(sa + w) * NPIX + m0 + j * 64 + lane) * 8,
                          &As[w * 1024 + j * 512]);
                gld_lds16(B3 + ((u64)(sb + w) * KC + nsub + j * 64 + lane) * 8,
                          &Bs[w * 1024 + j * 512]);
            }
            __syncthreads();               // vmcnt drain + barrier

            f16x8 af[4], bf[4];
#pragma unroll
            for (int m = 0; m < 4; ++m)
                af[m] = *(const f16x8*)&As[l4 * 1024 + (wr * 64 + m * 16 + l15) * 8];
#pragma unroll
            for (int n = 0; n < 4; ++n)
                bf[n] = *(const f16x8*)&Bs[l4 * 1024 + (wc * 64 + n * 16 + l15) * 8];
#pragma unroll
            for (int m = 0; m < 4; ++m)
#pragma unroll
                for (int n = 0; n < 4; ++n)
                    acc[m][n] = __builtin_amdgcn_mfma_f32_16x16x32_f16(
                        af[m], bf[n], acc[m][n], 0, 0, 0);
        }

        // ---- subtile epilogue: pack + running min ----
        const int cb = nsub + wc * 64 + l15;
        float cnv[4];
        int   col[4];
#pragma unroll
        for (int n = 0; n < 4; ++n) { col[n] = cb + n * 16; cnv[n] = cn[col[n]]; }
#pragma unroll
        for (int m = 0; m < 4; ++m)
#pragma unroll
            for (int r = 0; r < 4; ++r) {
                u64 best = rmin[m * 4 + r];
#pragma unroll
                for (int n = 0; n < 4; ++n) {
                    float dist = fmaf(-2.f, acc[m][n][r], cnv[n]) + 1024.f;
                    u64 p = ((u64)__float_as_uint(dist) << 32) | (u64)col[n];
                    best = (p < best) ? p : best;
                }
                rmin[m * 4 + r] = best;
            }
    }

    // ---- 16-lane reduce, one write per (group,row) ----
#pragma unroll
    for (int m = 0; m < 4; ++m)
#pragma unroll
        for (int r = 0; r < 4; ++r) {
            u64 v = rmin[m * 4 + r];
#pragma unroll
            for (int off = 1; off < 16; off <<= 1) {
                u64 o = __shfl_xor(v, off, 64);
                v = (o < v) ? o : v;
            }
            if (l15 == 0) {
                int row = m0 + wr * 64 + m * 16 + l4 * 4 + r;
                pk[(u64)(nb * 2 + wc) * NPIX + row] = v;
            }
        }
}

// ---------------------------------------------------------------------------
// Finalize: global top-2 candidates from 32 group minima, exact fp32
// recompute of both distances, strict-< / lowest-index pick, write outputs.
// ---------------------------------------------------------------------------
__global__ __launch_bounds__(256)
void vq_finalize(const float* __restrict__ x, const float* __restrict__ em,
                 const float* __restrict__ cn, const u64* __restrict__ pk,
                 float* __restrict__ out) {
    int n = blockIdx.x * 256 + threadIdx.x;
    u64 b1 = ~0ull, b2 = ~0ull;
#pragma unroll 4
    for (int g = 0; g < 32; ++g) {
        u64 v = pk[(u64)g * NPIX + n];
        if (v < b1)      { b2 = b1; b1 = v; }
        else if (v < b2) { b2 = v; }
    }
    int i1 = (int)(b1 & 0xffffffffull);
    int i2 = (int)(b2 & 0xffffffffull);

    float rn = 0.f, dot1 = 0.f, dot2 = 0.f;
#pragma unroll 8
    for (int d = 0; d < DD; ++d) {
        float xv = x[d * NPIX + n];
        rn   = fmaf(xv, xv, rn);
        dot1 = fmaf(xv, em[d * EMS + i1], dot1);
        dot2 = fmaf(xv, em[d * EMS + i2], dot2);
    }
    float D1 = rn + cn[i1] - 2.f * dot1;
    float D2 = rn + cn[i2] - 2.f * dot2;
    int bi; float db;
    if (D2 < D1 || (D2 == D1 && i2 < i1)) { bi = i2; db = D2; }
    else                                  { bi = i1; db = D1; }

    out[OUT_DMIN + n] = db;
    out[OUT_IND  + n] = (float)bi;
#pragma unroll 8
    for (int d = 0; d < DD; ++d)
        out[OUT_QUANT + d * NPIX + n] = em[d * EMS + bi];
}

// ---------------------------------------------------------------------------
extern "C" void kernel_launch(void* const* d_in, const int* in_sizes, int n_in,
                              void* d_out, int out_size, void* d_ws, size_t ws_size,
                              hipStream_t stream) {
    const float* x     = (const float*)d_in[0];   // [1,64,128,128]
    const float* embed = (const float*)d_in[1];   // [64,8193]
    const int*   cnt   = (const int*)d_in[2];     // [8192]
    float* out = (float*)d_out;

    // ws layout: A3 4MB | B3 2MB | pk 4MB | cn 32KB   (10.06 MB total)
    f16*   A3 = (f16*)d_ws;
    f16*   B3 = (f16*)((char*)d_ws + (size_t)4 * 1024 * 1024);
    u64*   pk = (u64*)((char*)d_ws + (size_t)6 * 1024 * 1024);
    float* cn = (float*)((char*)d_ws + (size_t)10 * 1024 * 1024);

    vq_prep_x<<<NPIX / 256, 256, 0, stream>>>(x, A3);
    vq_prep_e<<<KC / 256, 256, 0, stream>>>(embed, cnt, B3, cn);
    vq_mfma<<<128 * 16, 256, 0, stream>>>(A3, B3, cn, pk);
    vq_finalize<<<NPIX / 256, 256, 0, stream>>>(x, embed, cn, pk, out);
}